// Round 6
// baseline (253.702 us; speedup 1.0000x reference)
//
#include <hip/hip_runtime.h>
#include <hip/hip_bf16.h>
#include <math.h>

#define BB 4
#define TT 4096
#define CC 1024
#define HH 64

typedef __attribute__((ext_vector_type(8))) short short8;          // MFMA A/B frag (8 bf16)
typedef __attribute__((ext_vector_type(8))) unsigned short ushort8;
typedef __attribute__((ext_vector_type(4))) float f32x4;           // MFMA C/D frag
typedef __attribute__((ext_vector_type(4))) unsigned int uint4v;   // 16B mover
typedef __attribute__((ext_vector_type(2))) unsigned int uint2v;   // 8B mover

// RNE float->bf16
__device__ inline unsigned short f2bf(float f) {
    unsigned int u = __builtin_bit_cast(unsigned int, f);
    unsigned int r = u + 0x7fffu + ((u >> 16) & 1u);
    return (unsigned short)(r >> 16);
}

// scratch-slot offset within a batch for qt >= 32 (nc=2 for qt 32..63,
// 3 for 64..95, 4 for 96..127; total 288 slots/batch)
__device__ inline int slot_off(int qt) {
    if (qt < 64) return (qt - 32) * 2;
    if (qt < 96) return 64 + (qt - 64) * 3;
    return 160 + (qt - 96) * 4;
}

// ---------------------------------------------------------------------------
// Kernel 0: W -> frag-linear bf16 layout Wf.
// Wf[((kt*12 + ntl)*64 + lane)*8 + j] = W_{ntl>>2}[kt*32 + (lane>>4)*8 + j][(ntl&3)*16 + (lane&15)]
// ---------------------------------------------------------------------------
__global__ __launch_bounds__(256) void wtrans_kernel(
    const float* __restrict__ Wq,
    const float* __restrict__ Wk,
    const float* __restrict__ Wv,
    unsigned short* __restrict__ Wf)
{
    const int t = blockIdx.x * 256 + threadIdx.x;   // 0..24575
    const int lane = t & 63;
    const int ntl  = (t >> 6) % 12;
    const int kt   = t / 768;
    const int quad = lane >> 4, n = lane & 15;
    const int m    = ntl >> 2;
    const int col  = (ntl & 3) * 16 + n;
    const float* src = (m == 0) ? Wq : (m == 1) ? Wk : Wv;
    ushort8 u;
#pragma unroll
    for (int j = 0; j < 8; ++j)
        u[j] = f2bf(src[(kt * 32 + quad * 8 + j) * 64 + col]);
    *(ushort8*)(Wf + (size_t)t * 8) = u;
}

// ---------------------------------------------------------------------------
// Kernel 1: QKV GEMM [16384x1024]@[1024x192], barrier-free.
// 1024 blocks x 64 thr; wave = 16 rows x 192 cols (12 n-tiles).
// A-frags loaded directly from x (fp32->bf16 in reg, zero duplication across
// lanes, no LDS/no syncs -> compiler pipelines loads across kt iterations).
// Q written pre-scaled by C^-0.5 = 1/32.
// ---------------------------------------------------------------------------
__global__ __launch_bounds__(64) void qkv_gemm(
    const float* __restrict__ x,
    const unsigned short* __restrict__ Wf,
    unsigned short* __restrict__ Qb,
    unsigned short* __restrict__ Kb,
    unsigned short* __restrict__ Vb)
{
    const int lane = threadIdx.x;
    const int n    = lane & 15;
    const int quad = lane >> 4;
    const int row0 = blockIdx.x * 16;

    // lane (quad,n) owns A[m=n][k=quad*8..quad*8+7] per kt chunk
    const float* xp = x + (size_t)(row0 + n) * CC + quad * 8;

    f32x4 acc[12];
#pragma unroll
    for (int i = 0; i < 12; ++i) acc[i] = (f32x4){0.f, 0.f, 0.f, 0.f};

    for (int kt = 0; kt < 32; ++kt) {
        const float4 f0 = *(const float4*)(xp + kt * 32);
        const float4 f1 = *(const float4*)(xp + kt * 32 + 4);
        short8 a;
        a[0] = (short)f2bf(f0.x); a[1] = (short)f2bf(f0.y);
        a[2] = (short)f2bf(f0.z); a[3] = (short)f2bf(f0.w);
        a[4] = (short)f2bf(f1.x); a[5] = (short)f2bf(f1.y);
        a[6] = (short)f2bf(f1.z); a[7] = (short)f2bf(f1.w);

        const unsigned short* wp = Wf + ((size_t)(kt * 12) * 64 + lane) * 8;
#pragma unroll
        for (int ntl = 0; ntl < 12; ++ntl) {
            const short8 bw = *(const short8*)(wp + (size_t)ntl * 64 * 8);
            acc[ntl] = __builtin_amdgcn_mfma_f32_16x16x32_bf16(a, bw, acc[ntl], 0, 0, 0);
        }
    }

    // epilogue: D row = quad*4+r, col = n (within each 16x16 tile)
#pragma unroll
    for (int ntl = 0; ntl < 12; ++ntl) {
        const int m    = ntl >> 2;
        const int colb = (ntl & 3) * 16;
        unsigned short* dst = (m == 0) ? Qb : (m == 1) ? Kb : Vb;
        const float s = (m == 0) ? 0.03125f : 1.0f;
#pragma unroll
        for (int r = 0; r < 4; ++r) {
            const int row = row0 + quad * 4 + r;
            dst[(size_t)row * HH + colb + n] = f2bf(acc[ntl][r] * s);
        }
    }
}

// ---------------------------------------------------------------------------
// Kernel 2: flash attention, transposed (S^T = K Q^T, O^T = V^T P^T),
// split along s. Fixed-max softmax makes partials LINEAR: O_num and l
// simply add across s-chunks, so split-K needs no max merging.
// Grid = 4b x 128qt x 4chunk slots (2048); chunk = 16 s-tiles (1024 s).
// ci >= nc(qt) slots exit immediately. qt<=31 (nc==1): direct out write.
// qt>=32: write fp32 (O_num[32][64], l[32]) to scratch slot; combine later.
// ---------------------------------------------------------------------------
__global__ __launch_bounds__(128) void attn_kernel(
    const unsigned short* __restrict__ Qb,
    const unsigned short* __restrict__ Kb,
    const unsigned short* __restrict__ Vb,
    float* __restrict__ out,
    float* __restrict__ scr)
{
    const int b   = blockIdx.x >> 9;
    const int rem = blockIdx.x & 511;
    const int qt  = rem >> 2;
    const int ci  = rem & 3;
    const int stmax = qt >> 1;
    const int nc  = (stmax + 16) >> 4;          // ceil((stmax+1)/16)
    if (ci >= nc) return;
    const int st0   = ci << 4;
    const int stEnd = min(stmax, st0 + 15);

    __shared__ unsigned short Ks[64][72];     // K-tile  [s][h]
    __shared__ unsigned short Vt[64][72];     // V-tile  [h][s]
    __shared__ unsigned short Ps[2][16][72];  // per-wave P^T strip [qrow][s]

    const int tid  = threadIdx.x;
    const int lane = tid & 63;
    const int wave = tid >> 6;
    const int n    = lane & 15;
    const int quad = lane >> 4;

    const int qrow = qt * 32 + wave * 16 + n;   // this lane's q-row

    // Q^T B-frags resident (Q pre-scaled by 1/32)
    const unsigned short* qp = Qb + ((size_t)b * TT + qrow) * HH;
    const short8 bQ0 = *(const short8*)(qp + quad * 8);
    const short8 bQ1 = *(const short8*)(qp + 32 + quad * 8);

    f32x4 O[4];
#pragma unroll
    for (int ht = 0; ht < 4; ++ht) O[ht] = (f32x4){0.f, 0.f, 0.f, 0.f};
    float l = 0.f;

    // staging assignments (128 threads; each K-thread owns 32 shorts = 64 B)
    const int krow = tid >> 1;
    const int kch  = (tid & 1) * 32;
    const unsigned short* kbase = Kb + (size_t)b * TT * HH;
    const int vs0 = (tid & 31) * 2;
    const int vh0 = (tid >> 5) * 8;
    const unsigned short* vbase = Vb + (size_t)b * TT * HH;

    for (int st = st0; st <= stEnd; ++st) {
        const int sbase = st * 64;
        __syncthreads();

        {   // K-tile [64s][64h]
            const unsigned short* src = kbase + (size_t)(sbase + krow) * HH + kch;
            *(uint4v*)&Ks[krow][kch]      = *(const uint4v*)(src);
            *(uint4v*)&Ks[krow][kch + 8]  = *(const uint4v*)(src + 8);
            *(uint4v*)&Ks[krow][kch + 16] = *(const uint4v*)(src + 16);
            *(uint4v*)&Ks[krow][kch + 24] = *(const uint4v*)(src + 24);
        }
#pragma unroll
        for (int hh = 0; hh < 2; ++hh) {   // V-tile transposed
            const int h0 = vh0 + hh * 32;
            const unsigned short* s0p = vbase + (size_t)(sbase + vs0) * HH + h0;
            const ushort8 ra = *(const ushort8*)(s0p);
            const ushort8 rb = *(const ushort8*)(s0p + HH);
#pragma unroll
            for (int j = 0; j < 8; ++j) {
                const unsigned int pk = (unsigned int)ra[j] | ((unsigned int)rb[j] << 16);
                *(unsigned int*)&Vt[h0 + j][vs0] = pk;
            }
        }
        __syncthreads();

        // ---- S^T = K Q^T : 4 s-tiles, k = h = 64 ----
        f32x4 S[4];
#pragma unroll
        for (int mt = 0; mt < 4; ++mt) {
            const short8 a0 = *(const short8*)&Ks[mt * 16 + n][quad * 8];
            const short8 a1 = *(const short8*)&Ks[mt * 16 + n][32 + quad * 8];
            f32x4 acc = (f32x4){0.f, 0.f, 0.f, 0.f};
            acc = __builtin_amdgcn_mfma_f32_16x16x32_bf16(a0, bQ0, acc, 0, 0, 0);
            acc = __builtin_amdgcn_mfma_f32_16x16x32_bf16(a1, bQ1, acc, 0, 0, 0);
            S[mt] = acc;
        }

        // ---- causal mask (diag tile only; reached only by last chunk) ----
        if (st == stmax) {
#pragma unroll
            for (int mt = 0; mt < 4; ++mt) {
                const int sg = sbase + mt * 16 + quad * 4;
#pragma unroll
                for (int r = 0; r < 4; ++r)
                    if (sg + r > qrow) S[mt][r] = -INFINITY;
            }
        }

        // ---- per-lane softmax accumulate (fixed max; exp(-inf)=0) ----
#pragma unroll
        for (int mt = 0; mt < 4; ++mt)
#pragma unroll
            for (int r = 0; r < 4; ++r) {
                const float p = __expf(fminf(S[mt][r], 30.f));
                S[mt][r] = p;
                l += p;
            }

        // ---- P^T -> LDS strip [qrow][s] (4 x b64), read back as B-frags ----
#pragma unroll
        for (int mt = 0; mt < 4; ++mt) {
            uint2v w;
            w[0] = (unsigned int)f2bf(S[mt][0]) | ((unsigned int)f2bf(S[mt][1]) << 16);
            w[1] = (unsigned int)f2bf(S[mt][2]) | ((unsigned int)f2bf(S[mt][3]) << 16);
            *(uint2v*)&Ps[wave][n][mt * 16 + quad * 4] = w;
        }
        asm volatile("s_waitcnt lgkmcnt(0)" ::: "memory");   // wave-private strip
        const short8 bP0 = *(const short8*)&Ps[wave][n][quad * 8];
        const short8 bP1 = *(const short8*)&Ps[wave][n][32 + quad * 8];

        // ---- O^T += V^T P^T : 4 h-tiles, k = s = 64 ----
#pragma unroll
        for (int ht = 0; ht < 4; ++ht) {
            const short8 a0 = *(const short8*)&Vt[ht * 16 + n][quad * 8];
            const short8 a1 = *(const short8*)&Vt[ht * 16 + n][32 + quad * 8];
            O[ht] = __builtin_amdgcn_mfma_f32_16x16x32_bf16(a0, bP0, O[ht], 0, 0, 0);
            O[ht] = __builtin_amdgcn_mfma_f32_16x16x32_bf16(a1, bP1, O[ht], 0, 0, 0);
        }
    }

    // ---- l: reduce across the 4 quads holding this q-row (butterfly ->
    //      bit-identical in all quads) ----
    l += __shfl_xor(l, 16);
    l += __shfl_xor(l, 32);

    if (nc == 1) {
        const float inv = 1.0f / l;
        float* op = out + ((size_t)b * TT + qrow) * HH;
#pragma unroll
        for (int ht = 0; ht < 4; ++ht) {
            float4 o4;
            o4.x = O[ht][0] * inv;
            o4.y = O[ht][1] * inv;
            o4.z = O[ht][2] * inv;
            o4.w = O[ht][3] * inv;
            *(float4*)(op + ht * 16 + quad * 4) = o4;
        }
    } else {
        float* sb = scr + (size_t)(b * 288 + slot_off(qt) + ci) * 2080;
        float* op = sb + (wave * 16 + n) * 64;
#pragma unroll
        for (int ht = 0; ht < 4; ++ht)
            *(f32x4*)(op + ht * 16 + quad * 4) = O[ht];   // unnormalized
        if (quad == 0) sb[2048 + wave * 16 + n] = l;
    }
}

// ---------------------------------------------------------------------------
// Kernel 3: combine partial (O_num, l) for qt >= 32. 384 blocks x 128 thr.
// Thread = 1 row x 16 cols; sums <=4 slots, divides by total l.
// ---------------------------------------------------------------------------
__global__ __launch_bounds__(128) void combine_kernel(
    const float* __restrict__ scr,
    float* __restrict__ out)
{
    const int b  = blockIdx.x / 96;
    const int qt = 32 + blockIdx.x % 96;
    const int nc = ((qt >> 1) + 16) >> 4;
    const int base = b * 288 + slot_off(qt);

    const int t    = threadIdx.x;
    const int row  = t >> 2;
    const int col0 = (t & 3) * 16;

    f32x4 s0 = (f32x4){0.f,0.f,0.f,0.f}, s1 = s0, s2 = s0, s3 = s0;
    float lsum = 0.f;
    for (int ci = 0; ci < nc; ++ci) {
        const float* sb = scr + (size_t)(base + ci) * 2080;
        lsum += sb[2048 + row];
        const float* p = sb + row * 64 + col0;
        s0 += *(const f32x4*)(p);
        s1 += *(const f32x4*)(p + 4);
        s2 += *(const f32x4*)(p + 8);
        s3 += *(const f32x4*)(p + 12);
    }
    const float inv = 1.0f / lsum;
    float* op = out + ((size_t)b * TT + qt * 32 + row) * HH + col0;
    *(f32x4*)(op)      = s0 * inv;
    *(f32x4*)(op + 4)  = s1 * inv;
    *(f32x4*)(op + 8)  = s2 * inv;
    *(f32x4*)(op + 12) = s3 * inv;
}

// ---------------------------------------------------------------------------
extern "C" void kernel_launch(void* const* d_in, const int* in_sizes, int n_in,
                              void* d_out, int out_size, void* d_ws, size_t ws_size,
                              hipStream_t stream)
{
    const float* x  = (const float*)d_in[0];
    const float* Wq = (const float*)d_in[1];
    const float* Wk = (const float*)d_in[2];
    const float* Wv = (const float*)d_in[3];

    unsigned short* Qb = (unsigned short*)d_ws;            // 2 MB
    unsigned short* Kb = Qb + (size_t)BB * TT * HH;        // 2 MB
    unsigned short* Vb = Kb + (size_t)BB * TT * HH;        // 2 MB
    unsigned short* Wf = Vb + (size_t)BB * TT * HH;        // 384 KB
    float* scr = (float*)(Wf + (size_t)192 * 1024);        // 1152 slots x 8320 B = 9.6 MB
    float* out = (float*)d_out;

    wtrans_kernel<<<96, 256, 0, stream>>>(Wq, Wk, Wv, Wf);
    qkv_gemm<<<BB * TT / 16, 64, 0, stream>>>(x, Wf, Qb, Kb, Vb);
    attn_kernel<<<BB * 128 * 4, 128, 0, stream>>>(Qb, Kb, Vb, out, scr);
    combine_kernel<<<BB * 96, 128, 0, stream>>>(scr, out);
}

// Round 7
// 160.093 us; speedup vs baseline: 1.5847x; 1.5847x over previous
//
#include <hip/hip_runtime.h>
#include <hip/hip_bf16.h>
#include <math.h>

#define BB 4
#define TT 4096
#define CC 1024
#define HH 64

typedef __attribute__((ext_vector_type(8))) short short8;          // MFMA A/B frag (8 bf16)
typedef __attribute__((ext_vector_type(8))) unsigned short ushort8;
typedef __attribute__((ext_vector_type(4))) float f32x4;           // MFMA C/D frag
typedef __attribute__((ext_vector_type(2))) unsigned int uint2v;   // 8B mover

// RNE float->bf16
__device__ inline unsigned short f2bf(float f) {
    unsigned int u = __builtin_bit_cast(unsigned int, f);
    unsigned int r = u + 0x7fffu + ((u >> 16) & 1u);
    return (unsigned short)(r >> 16);
}

// scratch-slot offset within a batch for 16-row strip qs >= 64
// (nc=2 for qs 64..127, 3 for 128..191, 4 for 192..255; 576 slots/batch)
__device__ inline int soff_strip(int qs) {
    if (qs < 128) return (qs - 64) * 2;
    if (qs < 192) return 128 + (qs - 128) * 3;
    return 320 + (qs - 192) * 4;
}

// ---------------------------------------------------------------------------
// Kernel 0: W -> frag-linear bf16 layout Wf.
// Wf[((kt*12 + ntl)*64 + lane)*8 + j] = W_{ntl>>2}[kt*32 + (lane>>4)*8 + j][(ntl&3)*16 + (lane&15)]
// ---------------------------------------------------------------------------
__global__ __launch_bounds__(256) void wtrans_kernel(
    const float* __restrict__ Wq,
    const float* __restrict__ Wk,
    const float* __restrict__ Wv,
    unsigned short* __restrict__ Wf)
{
    const int t = blockIdx.x * 256 + threadIdx.x;   // 0..24575
    const int lane = t & 63;
    const int ntl  = (t >> 6) % 12;
    const int kt   = t / 768;
    const int quad = lane >> 4, n = lane & 15;
    const int m    = ntl >> 2;
    const int col  = (ntl & 3) * 16 + n;
    const float* src = (m == 0) ? Wq : (m == 1) ? Wk : Wv;
    ushort8 u;
#pragma unroll
    for (int j = 0; j < 8; ++j)
        u[j] = f2bf(src[(kt * 32 + quad * 8 + j) * 64 + col]);
    *(ushort8*)(Wf + (size_t)t * 8) = u;
}

// ---------------------------------------------------------------------------
// Kernel 1: QKV GEMM [16384x1024]@[1024x192], split-K over 4 waves.
// 1024 blocks x 256 thr; block = 16 rows x 192 cols; wave w covers
// k in [w*256, w*256+256) (8 kt chunks). LDS f32x4 reduce at the end.
// 16 waves/CU (vs R6's 4) -> latency hidden. Q pre-scaled by 1/32.
// ---------------------------------------------------------------------------
__global__ __launch_bounds__(256) void qkv_gemm(
    const float* __restrict__ x,
    const unsigned short* __restrict__ Wf,
    unsigned short* __restrict__ Qb,
    unsigned short* __restrict__ Kb,
    unsigned short* __restrict__ Vb)
{
    __shared__ f32x4 red[4][12][64];   // 48 KB

    const int tid  = threadIdx.x;
    const int lane = tid & 63;
    const int wave = tid >> 6;
    const int n    = lane & 15;
    const int quad = lane >> 4;
    const int row0 = blockIdx.x * 16;

    // lane (quad,n) owns A[m=n][k=quad*8..+7] within each kt chunk
    const float* xp = x + (size_t)(row0 + n) * CC + wave * 256 + quad * 8;

    f32x4 acc[12];
#pragma unroll
    for (int i = 0; i < 12; ++i) acc[i] = (f32x4){0.f, 0.f, 0.f, 0.f};

#pragma unroll
    for (int kt = 0; kt < 8; ++kt) {
        const float4 f0 = *(const float4*)(xp + kt * 32);
        const float4 f1 = *(const float4*)(xp + kt * 32 + 4);
        short8 a;
        a[0] = (short)f2bf(f0.x); a[1] = (short)f2bf(f0.y);
        a[2] = (short)f2bf(f0.z); a[3] = (short)f2bf(f0.w);
        a[4] = (short)f2bf(f1.x); a[5] = (short)f2bf(f1.y);
        a[6] = (short)f2bf(f1.z); a[7] = (short)f2bf(f1.w);

        const unsigned short* wp = Wf + ((size_t)((wave * 8 + kt) * 12) * 64 + lane) * 8;
#pragma unroll
        for (int ntl = 0; ntl < 12; ++ntl) {
            const short8 bw = *(const short8*)(wp + (size_t)ntl * 64 * 8);
            acc[ntl] = __builtin_amdgcn_mfma_f32_16x16x32_bf16(a, bw, acc[ntl], 0, 0, 0);
        }
    }

#pragma unroll
    for (int ntl = 0; ntl < 12; ++ntl) red[wave][ntl][lane] = acc[ntl];
    __syncthreads();

    // wave handles 3 n-tiles of the reduction + epilogue
#pragma unroll
    for (int i = 0; i < 3; ++i) {
        const int ntl = wave * 3 + i;
        f32x4 s = red[0][ntl][lane];
        s += red[1][ntl][lane];
        s += red[2][ntl][lane];
        s += red[3][ntl][lane];
        const int m    = ntl >> 2;
        const int colb = (ntl & 3) * 16;
        unsigned short* dst = (m == 0) ? Qb : (m == 1) ? Kb : Vb;
        const float sc = (m == 0) ? 0.03125f : 1.0f;
#pragma unroll
        for (int r = 0; r < 4; ++r) {
            const int row = row0 + quad * 4 + r;
            dst[(size_t)row * HH + colb + n] = f2bf(s[r] * sc);
        }
    }
}

// ---------------------------------------------------------------------------
// Kernel 1b: K/V -> frag-linear layouts (A-operand layouts, fixed per MFMA).
// Kf[r*8+j], r = ((b*64+st)*4+mt)*2+kk)*64+lane:
//   = Kb[b][st*64 + mt*16 + (lane&15)][kk*32 + (lane>>4)*8 + j]
// Vf[r*8+j] (same r nesting, tile=ht):
//   = Vb[b][st*64 + kk*32 + (lane>>4)*8 + j][ht*16 + (lane&15)]   (V^T frag)
// Makes every attn operand load ONE coalesced dwordx4 from L2 — no LDS staging.
// ---------------------------------------------------------------------------
__global__ __launch_bounds__(256) void kv_repack(
    const unsigned short* __restrict__ Kb,
    const unsigned short* __restrict__ Vb,
    unsigned short* __restrict__ Kf,
    unsigned short* __restrict__ Vf)
{
    const int t = blockIdx.x * 256 + threadIdx.x;   // 0..262143
    const int mat  = t >> 17;
    const int r    = t & 131071;
    const int lane = r & 63;
    const int kk   = (r >> 6) & 1;
    const int tile = (r >> 7) & 3;
    const int st   = (r >> 9) & 63;
    const int b    = r >> 15;
    const int n = lane & 15, quad = lane >> 4;

    if (mat == 0) {
        const unsigned short* src =
            Kb + ((size_t)b * TT + st * 64 + tile * 16 + n) * HH + kk * 32 + quad * 8;
        *(ushort8*)(Kf + (size_t)r * 8) = *(const ushort8*)src;
    } else {
        const int s0 = st * 64 + kk * 32 + quad * 8;
        const int h  = tile * 16 + n;
        ushort8 u;
#pragma unroll
        for (int j = 0; j < 8; ++j)
            u[j] = Vb[((size_t)b * TT + s0 + j) * HH + h];
        *(ushort8*)(Vf + (size_t)r * 8) = u;
    }
}

// ---------------------------------------------------------------------------
// Kernel 2: flash attention — barrier-free, wave-independent.
// Wave unit = (b, 16-row q-strip qs, s-chunk ci of 16 tiles).
// All K/V operands are coalesced dwordx4 A-frags from L2-hot Kf/Vf; the only
// LDS is the wave-private Ps transpose strip. Fixed-max softmax (linear
// partials -> split-s needs no max merge). Grid 1024 blocks x 4 waves.
// ---------------------------------------------------------------------------
__global__ __launch_bounds__(256) void attn_kernel(
    const unsigned short* __restrict__ Qb,
    const unsigned short* __restrict__ Kf,
    const unsigned short* __restrict__ Vf,
    float* __restrict__ out,
    float* __restrict__ scr)
{
    __shared__ unsigned short Ps[4][16][72];   // per-wave P strip [q][s], 9216 B

    const int tid  = threadIdx.x;
    const int lane = tid & 63;
    const int wave = tid >> 6;
    const int n    = lane & 15;
    const int quad = lane >> 4;

    const int wid = blockIdx.x * 4 + wave;
    const int b   = wid >> 10;
    const int rem = wid & 1023;
    const int qs  = rem >> 2;          // 16-row strip 0..255
    const int ci  = rem & 3;
    const int stmax = qs >> 2;
    const int nc  = (stmax + 16) >> 4; // ceil((stmax+1)/16)
    if (ci >= nc) return;
    const int st0   = ci << 4;
    const int stEnd = min(stmax, st0 + 15);

    const int qrow = qs * 16 + n;

    // Q^T B-frags resident (Q pre-scaled by 1/32)
    const unsigned short* qp = Qb + ((size_t)b * TT + qrow) * HH;
    const short8 bQ0 = *(const short8*)(qp + quad * 8);
    const short8 bQ1 = *(const short8*)(qp + 32 + quad * 8);

    const unsigned short* KfB = Kf + (size_t)b * 262144;
    const unsigned short* VfB = Vf + (size_t)b * 262144;

    f32x4 O[4];
#pragma unroll
    for (int ht = 0; ht < 4; ++ht) O[ht] = (f32x4){0.f, 0.f, 0.f, 0.f};
    float l = 0.f;

    for (int st = st0; st <= stEnd; ++st) {
        // ---- S^T = K Q^T : 4 s-tiles, k = h = 64; K A-frags direct from L2 ----
        f32x4 S[4];
#pragma unroll
        for (int mt = 0; mt < 4; ++mt) {
            const unsigned short* kp = KfB + (size_t)((st * 4 + mt) * 2) * 512 + lane * 8;
            const short8 a0 = *(const short8*)(kp);
            const short8 a1 = *(const short8*)(kp + 512);
            f32x4 acc = (f32x4){0.f, 0.f, 0.f, 0.f};
            acc = __builtin_amdgcn_mfma_f32_16x16x32_bf16(a0, bQ0, acc, 0, 0, 0);
            acc = __builtin_amdgcn_mfma_f32_16x16x32_bf16(a1, bQ1, acc, 0, 0, 0);
            S[mt] = acc;
        }

        // ---- causal mask (diag tile): element row = s, col = qrow ----
        if (st == stmax) {
#pragma unroll
            for (int mt = 0; mt < 4; ++mt) {
                const int sg = st * 64 + mt * 16 + quad * 4;
#pragma unroll
                for (int r = 0; r < 4; ++r)
                    if (sg + r > qrow) S[mt][r] = -INFINITY;
            }
        }

        // ---- per-lane softmax accumulate (fixed max; exp(-inf)=0) ----
#pragma unroll
        for (int mt = 0; mt < 4; ++mt)
#pragma unroll
            for (int r = 0; r < 4; ++r) {
                const float p = __expf(fminf(S[mt][r], 30.f));
                S[mt][r] = p;
                l += p;
            }

        // ---- P -> wave-private LDS strip [q][s], read back as B-frags ----
#pragma unroll
        for (int mt = 0; mt < 4; ++mt) {
            uint2v w;
            w[0] = (unsigned int)f2bf(S[mt][0]) | ((unsigned int)f2bf(S[mt][1]) << 16);
            w[1] = (unsigned int)f2bf(S[mt][2]) | ((unsigned int)f2bf(S[mt][3]) << 16);
            *(uint2v*)&Ps[wave][n][mt * 16 + quad * 4] = w;
        }
        asm volatile("s_waitcnt lgkmcnt(0)" ::: "memory");   // wave-private; no barrier
        const short8 bP0 = *(const short8*)&Ps[wave][n][quad * 8];
        const short8 bP1 = *(const short8*)&Ps[wave][n][32 + quad * 8];

        // ---- O^T += V^T P^T : 4 h-tiles; V^T A-frags direct from L2 ----
#pragma unroll
        for (int ht = 0; ht < 4; ++ht) {
            const unsigned short* vp = VfB + (size_t)((st * 4 + ht) * 2) * 512 + lane * 8;
            const short8 a0 = *(const short8*)(vp);
            const short8 a1 = *(const short8*)(vp + 512);
            O[ht] = __builtin_amdgcn_mfma_f32_16x16x32_bf16(a0, bP0, O[ht], 0, 0, 0);
            O[ht] = __builtin_amdgcn_mfma_f32_16x16x32_bf16(a1, bP1, O[ht], 0, 0, 0);
        }
    }

    // ---- l: reduce across the 4 quads holding this q-row ----
    l += __shfl_xor(l, 16);
    l += __shfl_xor(l, 32);

    if (nc == 1) {
        const float inv = 1.0f / l;
        float* op = out + ((size_t)b * TT + qrow) * HH;
#pragma unroll
        for (int ht = 0; ht < 4; ++ht) {
            float4 o4;
            o4.x = O[ht][0] * inv;
            o4.y = O[ht][1] * inv;
            o4.z = O[ht][2] * inv;
            o4.w = O[ht][3] * inv;
            *(float4*)(op + ht * 16 + quad * 4) = o4;
        }
    } else {
        float* sb = scr + (size_t)(b * 576 + soff_strip(qs) + ci) * 1040;
        float* rp = sb + n * 64;
#pragma unroll
        for (int ht = 0; ht < 4; ++ht)
            *(f32x4*)(rp + ht * 16 + quad * 4) = O[ht];   // unnormalized
        if (quad == 0) sb[1024 + n] = l;
    }
}

// ---------------------------------------------------------------------------
// Kernel 3: combine partials for strips qs >= 64. 768 blocks x 64 thr.
// ---------------------------------------------------------------------------
__global__ __launch_bounds__(64) void combine_kernel(
    const float* __restrict__ scr,
    float* __restrict__ out)
{
    const int b  = blockIdx.x / 192;
    const int qs = 64 + blockIdx.x % 192;
    const int nc = ((qs >> 2) + 16) >> 4;
    const int base = b * 576 + soff_strip(qs);

    const int t    = threadIdx.x;
    const int row  = t >> 2;
    const int col0 = (t & 3) * 16;

    f32x4 s0 = (f32x4){0.f,0.f,0.f,0.f}, s1 = s0, s2 = s0, s3 = s0;
    float lsum = 0.f;
    for (int ci = 0; ci < nc; ++ci) {
        const float* sb = scr + (size_t)(base + ci) * 1040;
        lsum += sb[1024 + row];
        const float* p = sb + row * 64 + col0;
        s0 += *(const f32x4*)(p);
        s1 += *(const f32x4*)(p + 4);
        s2 += *(const f32x4*)(p + 8);
        s3 += *(const f32x4*)(p + 12);
    }
    const float inv = 1.0f / lsum;
    float* op = out + ((size_t)b * TT + qs * 16 + row) * HH + col0;
    *(f32x4*)(op)      = s0 * inv;
    *(f32x4*)(op + 4)  = s1 * inv;
    *(f32x4*)(op + 8)  = s2 * inv;
    *(f32x4*)(op + 12) = s3 * inv;
}

// ---------------------------------------------------------------------------
// ws layout (15.96 MB, within R5's proven envelope). scr OVERLAYS Kb/Vb:
// safe because kv_repack (reads Kb/Vb) completes before attn (writes scr)
// on the same stream.
//   [Qb 2MB][ scr 9.585MB  (Kb 2MB, Vb 2MB live at its start until repack) ]
//   [Wf 384KB][Kf 2MB][Vf 2MB]
// ---------------------------------------------------------------------------
extern "C" void kernel_launch(void* const* d_in, const int* in_sizes, int n_in,
                              void* d_out, int out_size, void* d_ws, size_t ws_size,
                              hipStream_t stream)
{
    const float* x  = (const float*)d_in[0];
    const float* Wq = (const float*)d_in[1];
    const float* Wk = (const float*)d_in[2];
    const float* Wv = (const float*)d_in[3];

    unsigned short* Qb = (unsigned short*)d_ws;                    // 2 MB
    float*          scr = (float*)(Qb + (size_t)BB * TT * HH);     // 9.585 MB
    unsigned short* Kb  = (unsigned short*)scr;                    // 2 MB (dead after repack)
    unsigned short* Vb  = Kb + (size_t)BB * TT * HH;               // 2 MB (dead after repack)
    unsigned short* Wf  = (unsigned short*)((char*)scr + (size_t)BB * 576 * 1040 * 4); // 384 KB
    unsigned short* Kf  = Wf + (size_t)192 * 1024;                 // 2 MB
    unsigned short* Vf  = Kf + (size_t)BB * 262144;                // 2 MB
    float* out = (float*)d_out;

    wtrans_kernel<<<96, 256, 0, stream>>>(Wq, Wk, Wv, Wf);
    qkv_gemm<<<BB * TT / 16, 256, 0, stream>>>(x, Wf, Qb, Kb, Vb);
    kv_repack<<<1024, 256, 0, stream>>>(Kb, Vb, Kf, Vf);
    attn_kernel<<<1024, 256, 0, stream>>>(Qb, Kf, Vf, out, scr);
    combine_kernel<<<768, 64, 0, stream>>>(scr, out);
}